// Round 2
// baseline (213.119 us; speedup 1.0000x reference)
//
#include <hip/hip_runtime.h>

// Problem shape (fixed by the reference setup_inputs)
constexpr int B = 16, F = 16, H = 256, W = 256;
constexpr int HW = H * W;               // 65536
constexpr int SPATIAL = B * HW;         // 1,048,576 per-feature element count
constexpr int PLANE4 = HW / 4;          // 16384 float4 (or mask-dwords) per (b,f) plane
constexpr int BSTRIDE4 = F * PLANE4;    // 262144 per batch index
constexpr int FQ = 4;                   // features per quarter-wave

constexpr int NBLK = 512;               // grid size (no co-residency requirement)
constexpr int NTHREADS = 512;           // 8 waves/block
constexpr int NWAVES = NTHREADS / 64;
constexpr int TOTG = B * PLANE4;        // 262144 groups (group = 4 pixels x 16 features)
constexpr int SLOTS = NBLK * NWAVES * 16;   // 65536 (wave,l16) slots per sweep
constexpr int G = TOTG / SLOTS;         // 4 groups per thread
static_assert(TOTG % SLOTS == 0, "grid-stride must divide evenly");

// 50 values: s[16], c[16], dtot[16], sall_tot, call.
// (sall collapsed to a scalar: all features share denominator `call`.)
constexpr int NVALS = 50;

// R10: R9's algorithmic content (grid-stride x4 + 2-deep register prefetch +
// sall scalar collapse) but WITHOUT cooperative launch (graph-capture hazard,
// container died twice). Single-pass finalize via device-scope atomic counter:
// the last block to finish reduces the 50x512 partials. Agent-scope atomics
// handle cross-XCD L2 non-coherence; counter zeroed by hipMemsetAsync.
__global__ __launch_bounds__(NTHREADS, 4) void heatloss_fused(
        const float4* __restrict__ inp, const float4* __restrict__ tgt,
        const unsigned int* __restrict__ msk, float* __restrict__ partials,
        int* __restrict__ counter, float* __restrict__ out) {
    const int tid  = threadIdx.x;
    const int wave = tid >> 6;
    const int lane = tid & 63;
    const int l16  = lane & 15;
    const int q    = lane >> 4;              // quarter: features q*4 .. q*4+3
    const int slot0 = (blockIdx.x * NWAVES + wave) * 16 + l16;
    const int qoff  = q * (FQ * PLANE4);

    float s[FQ]  = {0.f, 0.f, 0.f, 0.f};
    float c[FQ]  = {0.f, 0.f, 0.f, 0.f};
    float dt[FQ] = {0.f, 0.f, 0.f, 0.f};
    float sall = 0.f, call = 0.f;

    // 2-deep register double buffer (all indices compile-time after unroll)
    unsigned int mb[2][FQ];
    float4 ab[2][FQ], tb[2][FQ];

    {   // prologue: load group 0
        const int slot = slot0;
        const int base = (slot >> 14) * BSTRIDE4 + (slot & (PLANE4 - 1)) + qoff;
        #pragma unroll
        for (int j = 0; j < FQ; j++) mb[0][j] = msk[base + j * PLANE4];
        #pragma unroll
        for (int j = 0; j < FQ; j++) ab[0][j] = inp[base + j * PLANE4];
        #pragma unroll
        for (int j = 0; j < FQ; j++) tb[0][j] = tgt[base + j * PLANE4];
    }

    #pragma unroll
    for (int it = 0; it < G; ++it) {
        const int cur = it & 1, nxt = cur ^ 1;
        if (it + 1 < G) {   // prefetch next group while consuming current
            const int slot = slot0 + (it + 1) * SLOTS;
            const int base = (slot >> 14) * BSTRIDE4 + (slot & (PLANE4 - 1)) + qoff;
            #pragma unroll
            for (int j = 0; j < FQ; j++) mb[nxt][j] = msk[base + j * PLANE4];
            #pragma unroll
            for (int j = 0; j < FQ; j++) ab[nxt][j] = inp[base + j * PLANE4];
            #pragma unroll
            for (int j = 0; j < FQ; j++) tb[nxt][j] = tgt[base + j * PLANE4];
        }

        unsigned int anyu = mb[cur][0] | mb[cur][1] | mb[cur][2] | mb[cur][3];
        anyu |= __shfl_xor(anyu, 16, 64);    // combine quarters...
        anyu |= __shfl_xor(anyu, 32, 64);    // ...-> any over all 16 features
        const float af0 = (anyu & 0x000000FFu) ? 1.f : 0.f;
        const float af1 = (anyu & 0x0000FF00u) ? 1.f : 0.f;
        const float af2 = (anyu & 0x00FF0000u) ? 1.f : 0.f;
        const float af3 = (anyu & 0xFF000000u) ? 1.f : 0.f;
        if (q == 0) call += (af0 + af1) + (af2 + af3);   // count each pixel once

        #pragma unroll
        for (int j = 0; j < FQ; j++) {
            const float4 a = ab[cur][j];
            const float4 t = tb[cur][j];
            const float d0 = fabsf(a.x - t.x);
            const float d1 = fabsf(a.y - t.y);
            const float d2 = fabsf(a.z - t.z);
            const float d3 = fabsf(a.w - t.w);
            const unsigned int mm = mb[cur][j];
            const float m0 = (float)( mm        & 0xFFu);
            const float m1 = (float)((mm >> 8)  & 0xFFu);
            const float m2 = (float)((mm >> 16) & 0xFFu);
            const float m3 = (float)( mm >> 24);
            dt[j] += (d0 + d1) + (d2 + d3);
            s[j]  += m0 * d0 + m1 * d1 + m2 * d2 + m3 * d3;
            c[j]  += (m0 + m1) + (m2 + m3);
            sall  += af0 * d0 + af1 * d1 + af2 * d2 + af3 * d3;
        }
    }

    // Width-16 reduction for per-feature values (quarters hold disjoint features)
    __shared__ float red[NWAVES][NVALS];
    const int fbase = q * FQ;
    #pragma unroll
    for (int j = 0; j < FQ; j++) {
        float xs = s[j], xc = c[j], xd = dt[j];
        #pragma unroll
        for (int o = 8; o > 0; o >>= 1) {
            xs += __shfl_down(xs, o, 16);
            xc += __shfl_down(xc, o, 16);
            xd += __shfl_down(xd, o, 16);
        }
        if (l16 == 0) {
            red[wave][ 0 + fbase + j] = xs;
            red[wave][16 + fbase + j] = xc;
            red[wave][32 + fbase + j] = xd;
        }
    }
    // Full-wave reduction for the two scalars
    float xa = sall, xcl = call;
    #pragma unroll
    for (int o = 32; o > 0; o >>= 1) {
        xa  += __shfl_down(xa,  o, 64);
        xcl += __shfl_down(xcl, o, 64);
    }
    if (lane == 0) { red[wave][48] = xa; red[wave][49] = xcl; }
    __syncthreads();

    // Publish this block's 50 partials at the coherent point (agent scope:
    // sc0/sc1 stores are visible across XCD L2s).
    if (tid < NVALS) {
        float t = 0.f;
        #pragma unroll
        for (int w2 = 0; w2 < NWAVES; w2++) t += red[w2][tid];
        __hip_atomic_store(&partials[tid * NBLK + blockIdx.x], t,
                           __ATOMIC_RELAXED, __HIP_MEMORY_SCOPE_AGENT);
    }
    __syncthreads();   // barrier drains vmcnt -> all 50 stores retired

    // Last-finishing block does the finalize. No waiting, no deadlock risk.
    __shared__ int lastflag;
    if (tid == 0) {
        const int old = __hip_atomic_fetch_add(counter, 1, __ATOMIC_ACQ_REL,
                                               __HIP_MEMORY_SCOPE_AGENT);
        lastflag = (old == NBLK - 1) ? 1 : 0;
    }
    __syncthreads();

    if (lastflag) {
        __shared__ float vals[NVALS];
        for (int v = wave; v < NVALS; v += NWAVES) {
            const float* p = partials + v * NBLK;
            float x = 0.f;
            #pragma unroll
            for (int k = 0; k < NBLK / 64; k++)
                x += __hip_atomic_load(p + lane + k * 64,
                                       __ATOMIC_RELAXED, __HIP_MEMORY_SCOPE_AGENT);
            #pragma unroll
            for (int o = 32; o > 0; o >>= 1) x += __shfl_down(x, o, 64);
            if (lane == 0) vals[v] = x;
        }
        __syncthreads();
        if (tid == 0) {
            const float Nf = (float)SPATIAL;
            float lf = 0.f, lbg = 0.f;
            #pragma unroll
            for (int f = 0; f < F; f++) {
                const float sf = vals[f], cf = vals[16 + f], dtf = vals[32 + f];
                lf += (cf > 0.f) ? sf / cf : 0.f;
                const float sbg = dtf - sf, cbg = Nf - cf;
                lbg += (cbg > 0.f) ? sbg / cbg : 0.f;
            }
            const float sa = vals[48], cl = vals[49];
            const float lall = (cl > 0.f) ? sa / cl : 0.f;  // == mean_f(sa_f/call)*16
            out[0] = (lf / 16.f + lbg / 16.f + lall / 16.f) / 3.f;
        }
    }
}

extern "C" void kernel_launch(void* const* d_in, const int* in_sizes, int n_in,
                              void* d_out, int out_size, void* d_ws, size_t ws_size,
                              hipStream_t stream) {
    const float4*       inp = (const float4*)d_in[0];
    const float4*       tgt = (const float4*)d_in[1];
    const unsigned int* msk = (const unsigned int*)d_in[2];   // jnp.bool_ -> 1 byte each
    float* out      = (float*)d_out;
    float* partials = (float*)d_ws;                  // [50][512] = 100 KB
    int*   counter  = (int*)(partials + NVALS * NBLK);

    hipMemsetAsync(counter, 0, sizeof(int), stream); // re-poison-safe zeroing
    heatloss_fused<<<NBLK, NTHREADS, 0, stream>>>(inp, tgt, msk, partials,
                                                  counter, out);
}

// Round 3
// 200.082 us; speedup vs baseline: 1.0652x; 1.0652x over previous
//
#include <hip/hip_runtime.h>

// Problem shape (fixed by the reference setup_inputs)
constexpr int B = 16, F = 16, H = 256, W = 256;
constexpr int HW = H * W;               // 65536
constexpr int SPATIAL = B * HW;         // 1,048,576 per-feature element count
constexpr int PLANE4 = HW / 4;          // 16384 float4 (or mask-dwords) per (b,f) plane
constexpr int BSTRIDE4 = F * PLANE4;    // 262144 per batch index
constexpr int FQ = 4;                   // features per quarter-wave

constexpr int NBLK = 512;               // grid size (no co-residency requirement)
constexpr int NTHREADS = 512;           // 8 waves/block
constexpr int NWAVES = NTHREADS / 64;
constexpr int TOTG = B * PLANE4;        // 262144 groups (group = 4 pixels x 16 features)
constexpr int SLOTS = NBLK * NWAVES * 16;   // 65536 (wave,l16) slots per sweep
constexpr int G = TOTG / SLOTS;         // 4 groups per thread
static_assert(G == 4, "pipeline below is hand-scheduled for G==4");

// 50 values: s[16], c[16], dtot[16], sall_tot, call.
constexpr int NVALS = 50;

// R11: R10's fusion was right (saved ~12us of dispatch overhead) but
// __launch_bounds__(512,4) clamped VGPR to 64 -> the 72-dword double buffer
// spilled to scratch (WRITE_SIZE 4.2->22.3 MB proved it; main 56.7->96.5us).
// Fix: min-waves 2 (VGPR cap 256) so the ~100-reg double-buffer LIVES in
// registers; prologue issues TWO full 12-load batches (24 loads in flight)
// before the first consume, steady-state 1-ahead.
struct Buf {
    unsigned int m[FQ];
    float4 a[FQ];
    float4 t[FQ];
};

__global__ __launch_bounds__(NTHREADS, 2) void heatloss_fused(
        const float4* __restrict__ inp, const float4* __restrict__ tgt,
        const unsigned int* __restrict__ msk, float* __restrict__ partials,
        int* __restrict__ counter, float* __restrict__ out) {
    const int tid  = threadIdx.x;
    const int wave = tid >> 6;
    const int lane = tid & 63;
    const int l16  = lane & 15;
    const int q    = lane >> 4;              // quarter: features q*4 .. q*4+3
    const int slot0 = (blockIdx.x * NWAVES + wave) * 16 + l16;
    const int qoff  = q * (FQ * PLANE4);

    float s[FQ]  = {0.f, 0.f, 0.f, 0.f};
    float c[FQ]  = {0.f, 0.f, 0.f, 0.f};
    float dt[FQ] = {0.f, 0.f, 0.f, 0.f};
    float sall = 0.f, call = 0.f;

    auto load_group = [&](Buf& bf, int it) {
        const int slot = slot0 + it * SLOTS;
        const int base = (slot >> 14) * BSTRIDE4 + (slot & (PLANE4 - 1)) + qoff;
        #pragma unroll
        for (int j = 0; j < FQ; j++) bf.m[j] = msk[base + j * PLANE4];
        #pragma unroll
        for (int j = 0; j < FQ; j++) bf.a[j] = inp[base + j * PLANE4];
        #pragma unroll
        for (int j = 0; j < FQ; j++) bf.t[j] = tgt[base + j * PLANE4];
    };

    auto consume = [&](const Buf& bf) {
        unsigned int anyu = bf.m[0] | bf.m[1] | bf.m[2] | bf.m[3];
        anyu |= __shfl_xor(anyu, 16, 64);    // combine quarters...
        anyu |= __shfl_xor(anyu, 32, 64);    // ...-> any over all 16 features
        const float af0 = (anyu & 0x000000FFu) ? 1.f : 0.f;
        const float af1 = (anyu & 0x0000FF00u) ? 1.f : 0.f;
        const float af2 = (anyu & 0x00FF0000u) ? 1.f : 0.f;
        const float af3 = (anyu & 0xFF000000u) ? 1.f : 0.f;
        if (q == 0) call += (af0 + af1) + (af2 + af3);   // count each pixel once

        #pragma unroll
        for (int j = 0; j < FQ; j++) {
            const float4 a = bf.a[j];
            const float4 t = bf.t[j];
            const float d0 = fabsf(a.x - t.x);
            const float d1 = fabsf(a.y - t.y);
            const float d2 = fabsf(a.z - t.z);
            const float d3 = fabsf(a.w - t.w);
            const unsigned int mm = bf.m[j];
            const float m0 = (float)( mm        & 0xFFu);
            const float m1 = (float)((mm >> 8)  & 0xFFu);
            const float m2 = (float)((mm >> 16) & 0xFFu);
            const float m3 = (float)( mm >> 24);
            dt[j] += (d0 + d1) + (d2 + d3);
            s[j]  += m0 * d0 + m1 * d1 + m2 * d2 + m3 * d3;
            c[j]  += (m0 + m1) + (m2 + m3);
            sall  += af0 * d0 + af1 * d1 + af2 * d2 + af3 * d3;
        }
    };

    // Hand-scheduled G=4 pipeline: 2 batches in flight at the start,
    // steady-state 1-ahead. All buffer indices are compile-time (rule #20).
    Buf b0, b1;
    load_group(b0, 0);
    load_group(b1, 1);      // 24 loads in flight before first wait
    consume(b0);
    load_group(b0, 2);
    consume(b1);
    load_group(b1, 3);
    consume(b0);
    consume(b1);

    // Width-16 reduction for per-feature values (quarters hold disjoint features)
    __shared__ float red[NWAVES][NVALS];
    const int fbase = q * FQ;
    #pragma unroll
    for (int j = 0; j < FQ; j++) {
        float xs = s[j], xc = c[j], xd = dt[j];
        #pragma unroll
        for (int o = 8; o > 0; o >>= 1) {
            xs += __shfl_down(xs, o, 16);
            xc += __shfl_down(xc, o, 16);
            xd += __shfl_down(xd, o, 16);
        }
        if (l16 == 0) {
            red[wave][ 0 + fbase + j] = xs;
            red[wave][16 + fbase + j] = xc;
            red[wave][32 + fbase + j] = xd;
        }
    }
    // Full-wave reduction for the two scalars
    float xa = sall, xcl = call;
    #pragma unroll
    for (int o = 32; o > 0; o >>= 1) {
        xa  += __shfl_down(xa,  o, 64);
        xcl += __shfl_down(xcl, o, 64);
    }
    if (lane == 0) { red[wave][48] = xa; red[wave][49] = xcl; }
    __syncthreads();

    // Publish this block's 50 partials at the coherent point (agent scope:
    // visible across XCD L2s).
    if (tid < NVALS) {
        float t = 0.f;
        #pragma unroll
        for (int w2 = 0; w2 < NWAVES; w2++) t += red[w2][tid];
        __hip_atomic_store(&partials[tid * NBLK + blockIdx.x], t,
                           __ATOMIC_RELAXED, __HIP_MEMORY_SCOPE_AGENT);
    }
    __syncthreads();   // all 50 stores retired before the counter bump

    // Last-finishing block does the finalize. No waiting, no deadlock risk.
    __shared__ int lastflag;
    if (tid == 0) {
        const int old = __hip_atomic_fetch_add(counter, 1, __ATOMIC_ACQ_REL,
                                               __HIP_MEMORY_SCOPE_AGENT);
        lastflag = (old == NBLK - 1) ? 1 : 0;
    }
    __syncthreads();

    if (lastflag) {
        __shared__ float vals[NVALS];
        for (int v = wave; v < NVALS; v += NWAVES) {
            const float* p = partials + v * NBLK;
            float x = 0.f;
            #pragma unroll
            for (int k = 0; k < NBLK / 64; k++)
                x += __hip_atomic_load(p + lane + k * 64,
                                       __ATOMIC_RELAXED, __HIP_MEMORY_SCOPE_AGENT);
            #pragma unroll
            for (int o = 32; o > 0; o >>= 1) x += __shfl_down(x, o, 64);
            if (lane == 0) vals[v] = x;
        }
        __syncthreads();
        if (tid == 0) {
            const float Nf = (float)SPATIAL;
            float lf = 0.f, lbg = 0.f;
            #pragma unroll
            for (int f = 0; f < F; f++) {
                const float sf = vals[f], cf = vals[16 + f], dtf = vals[32 + f];
                lf += (cf > 0.f) ? sf / cf : 0.f;
                const float sbg = dtf - sf, cbg = Nf - cf;
                lbg += (cbg > 0.f) ? sbg / cbg : 0.f;
            }
            const float sa = vals[48], cl = vals[49];
            const float lall = (cl > 0.f) ? sa / cl : 0.f;
            out[0] = (lf / 16.f + lbg / 16.f + lall / 16.f) / 3.f;
        }
    }
}

extern "C" void kernel_launch(void* const* d_in, const int* in_sizes, int n_in,
                              void* d_out, int out_size, void* d_ws, size_t ws_size,
                              hipStream_t stream) {
    const float4*       inp = (const float4*)d_in[0];
    const float4*       tgt = (const float4*)d_in[1];
    const unsigned int* msk = (const unsigned int*)d_in[2];   // jnp.bool_ -> 1 byte each
    float* out      = (float*)d_out;
    float* partials = (float*)d_ws;                  // [50][512] = 100 KB
    int*   counter  = (int*)(partials + NVALS * NBLK);

    hipMemsetAsync(counter, 0, sizeof(int), stream); // re-poison-safe zeroing
    heatloss_fused<<<NBLK, NTHREADS, 0, stream>>>(inp, tgt, msk, partials,
                                                  counter, out);
}

// Round 4
// 187.392 us; speedup vs baseline: 1.1373x; 1.0677x over previous
//
#include <hip/hip_runtime.h>

// Problem shape (fixed by the reference setup_inputs)
constexpr int B = 16, F = 16, H = 256, W = 256;
constexpr int HW = H * W;               // 65536
constexpr int SPATIAL = B * HW;         // 1,048,576 per-feature element count
constexpr int PLANE4 = HW / 4;          // 16384 float4 (or mask-dwords) per (b,f) plane
constexpr int BSTRIDE4 = F * PLANE4;    // 262144 per batch index
constexpr int FQ = 4;                   // features per quarter-wave

constexpr int NBLK = 512;               // 2 blocks/CU at VGPR<=128
constexpr int NTHREADS = 512;           // 8 waves/block
constexpr int NWAVES = NTHREADS / 64;
constexpr int TOTG = B * PLANE4;        // 262144 groups (group = 4 pixels x 16 features)
constexpr int SLOTS = NBLK * NWAVES * 16;   // 65536 (wave,l16) slots per sweep
constexpr int G = TOTG / SLOTS;         // 4 groups per thread
static_assert(G == 4, "pipeline below is hand-scheduled for G==4");

// 50 values: s[16], c[16], dtot[16], sall_tot, call.
constexpr int NVALS = 50;

// R12: R11's pipeline is kept (VGPR=76, zero spill — validated). The atomic
// last-block election is DROPPED: 512 same-address agent-scope fetch_adds
// serialized into a ~40us idle tail (evidence: occupancy 54%->15%, and a
// fully-LLC-resident replay pass with hbm_bytes=0.8MB still took 73us ->
// duration insensitive to memory, i.e. serialization-bound). Finalize moves
// back to a tiny second kernel; kernel boundary provides coherence, so
// partials use plain stores. Cost: +1 dispatch (~5-10us) vs -40us tail.
struct Buf {
    unsigned int m[FQ];
    float4 a[FQ];
    float4 t[FQ];
};

__global__ __launch_bounds__(NTHREADS, 2) void heatloss_main(
        const float4* __restrict__ inp, const float4* __restrict__ tgt,
        const unsigned int* __restrict__ msk, float* __restrict__ partials) {
    const int tid  = threadIdx.x;
    const int wave = tid >> 6;
    const int lane = tid & 63;
    const int l16  = lane & 15;
    const int q    = lane >> 4;              // quarter: features q*4 .. q*4+3
    const int slot0 = (blockIdx.x * NWAVES + wave) * 16 + l16;
    const int qoff  = q * (FQ * PLANE4);

    float s[FQ]  = {0.f, 0.f, 0.f, 0.f};
    float c[FQ]  = {0.f, 0.f, 0.f, 0.f};
    float dt[FQ] = {0.f, 0.f, 0.f, 0.f};
    float sall = 0.f, call = 0.f;

    auto load_group = [&](Buf& bf, int it) {
        const int slot = slot0 + it * SLOTS;
        const int base = (slot >> 14) * BSTRIDE4 + (slot & (PLANE4 - 1)) + qoff;
        #pragma unroll
        for (int j = 0; j < FQ; j++) bf.m[j] = msk[base + j * PLANE4];
        #pragma unroll
        for (int j = 0; j < FQ; j++) bf.a[j] = inp[base + j * PLANE4];
        #pragma unroll
        for (int j = 0; j < FQ; j++) bf.t[j] = tgt[base + j * PLANE4];
    };

    auto consume = [&](const Buf& bf) {
        unsigned int anyu = bf.m[0] | bf.m[1] | bf.m[2] | bf.m[3];
        anyu |= __shfl_xor(anyu, 16, 64);    // combine quarters...
        anyu |= __shfl_xor(anyu, 32, 64);    // ...-> any over all 16 features
        const float af0 = (anyu & 0x000000FFu) ? 1.f : 0.f;
        const float af1 = (anyu & 0x0000FF00u) ? 1.f : 0.f;
        const float af2 = (anyu & 0x00FF0000u) ? 1.f : 0.f;
        const float af3 = (anyu & 0xFF000000u) ? 1.f : 0.f;
        if (q == 0) call += (af0 + af1) + (af2 + af3);   // count each pixel once

        #pragma unroll
        for (int j = 0; j < FQ; j++) {
            const float4 a = bf.a[j];
            const float4 t = bf.t[j];
            const float d0 = fabsf(a.x - t.x);
            const float d1 = fabsf(a.y - t.y);
            const float d2 = fabsf(a.z - t.z);
            const float d3 = fabsf(a.w - t.w);
            const unsigned int mm = bf.m[j];
            const float m0 = (float)( mm        & 0xFFu);
            const float m1 = (float)((mm >> 8)  & 0xFFu);
            const float m2 = (float)((mm >> 16) & 0xFFu);
            const float m3 = (float)( mm >> 24);
            dt[j] += (d0 + d1) + (d2 + d3);
            s[j]  += m0 * d0 + m1 * d1 + m2 * d2 + m3 * d3;
            c[j]  += (m0 + m1) + (m2 + m3);
            sall  += af0 * d0 + af1 * d1 + af2 * d2 + af3 * d3;
        }
    };

    // Hand-scheduled G=4 pipeline: 2 batches in flight at the start,
    // steady-state 1-ahead. All buffer indices are compile-time (rule #20).
    Buf b0, b1;
    load_group(b0, 0);
    load_group(b1, 1);      // 24 loads in flight before first wait
    consume(b0);
    load_group(b0, 2);
    consume(b1);
    load_group(b1, 3);
    consume(b0);
    consume(b1);

    // Width-16 reduction for per-feature values (quarters hold disjoint features)
    __shared__ float red[NWAVES][NVALS];
    const int fbase = q * FQ;
    #pragma unroll
    for (int j = 0; j < FQ; j++) {
        float xs = s[j], xc = c[j], xd = dt[j];
        #pragma unroll
        for (int o = 8; o > 0; o >>= 1) {
            xs += __shfl_down(xs, o, 16);
            xc += __shfl_down(xc, o, 16);
            xd += __shfl_down(xd, o, 16);
        }
        if (l16 == 0) {
            red[wave][ 0 + fbase + j] = xs;
            red[wave][16 + fbase + j] = xc;
            red[wave][32 + fbase + j] = xd;
        }
    }
    // Full-wave reduction for the two scalars
    float xa = sall, xcl = call;
    #pragma unroll
    for (int o = 32; o > 0; o >>= 1) {
        xa  += __shfl_down(xa,  o, 64);
        xcl += __shfl_down(xcl, o, 64);
    }
    if (lane == 0) { red[wave][48] = xa; red[wave][49] = xcl; }
    __syncthreads();

    if (tid < NVALS) {
        float t = 0.f;
        #pragma unroll
        for (int w2 = 0; w2 < NWAVES; w2++) t += red[w2][tid];
        partials[tid * NBLK + blockIdx.x] = t;   // layout [50][NBLK]
    }
}

// Finalize: one block sums the 50x512 partials and emits the loss.
__global__ __launch_bounds__(NTHREADS) void heatloss_final(
        const float* __restrict__ partials, float* __restrict__ out) {
    const int tid  = threadIdx.x;
    const int wave = tid >> 6;
    const int lane = tid & 63;
    __shared__ float vals[NVALS];
    for (int v = wave; v < NVALS; v += NWAVES) {
        const float* p = partials + v * NBLK;
        float x = 0.f;
        #pragma unroll
        for (int k = 0; k < NBLK / 64; k++) x += p[lane + k * 64];
        #pragma unroll
        for (int o = 32; o > 0; o >>= 1) x += __shfl_down(x, o, 64);
        if (lane == 0) vals[v] = x;
    }
    __syncthreads();
    if (tid == 0) {
        const float Nf = (float)SPATIAL;
        float lf = 0.f, lbg = 0.f;
        #pragma unroll
        for (int f = 0; f < F; f++) {
            const float sf = vals[f], cf = vals[16 + f], dtf = vals[32 + f];
            lf += (cf > 0.f) ? sf / cf : 0.f;
            const float sbg = dtf - sf, cbg = Nf - cf;
            lbg += (cbg > 0.f) ? sbg / cbg : 0.f;
        }
        const float sa = vals[48], cl = vals[49];
        const float lall = (cl > 0.f) ? sa / cl : 0.f;  // == mean_f(sa_f/call)*16
        out[0] = (lf / 16.f + lbg / 16.f + lall / 16.f) / 3.f;
    }
}

extern "C" void kernel_launch(void* const* d_in, const int* in_sizes, int n_in,
                              void* d_out, int out_size, void* d_ws, size_t ws_size,
                              hipStream_t stream) {
    const float4*       inp = (const float4*)d_in[0];
    const float4*       tgt = (const float4*)d_in[1];
    const unsigned int* msk = (const unsigned int*)d_in[2];   // jnp.bool_ -> 1 byte each
    float* out      = (float*)d_out;
    float* partials = (float*)d_ws;                  // [50][512] = 100 KB

    heatloss_main<<<NBLK, NTHREADS, 0, stream>>>(inp, tgt, msk, partials);
    heatloss_final<<<1, NTHREADS, 0, stream>>>(partials, out);
}